// Round 2
// baseline (518.506 us; speedup 1.0000x reference)
//
#include <hip/hip_runtime.h>

// MMEAttn decode: B=64, QT=1, KVT=256, M=32, H=128, fp32.
// Flash-decode split-KV: each block streams CONTIGUOUS k/v rows
// [b, t0:t0+TBLK, :] (all 32 heads), so every wave load is a 1KB
// contiguous segment. Partials (max, sum, out) combined in kernel 2.

constexpr int B    = 64;
constexpr int KVT  = 256;
constexpr int Mh   = 32;
constexpr int H    = 128;
constexpr int MH   = Mh * H;          // 4096 floats per row
constexpr int MH4  = MH / 4;          // 1024 float4
constexpr int SPLIT = 16;
constexpr int TBLK  = KVT / SPLIT;    // 16 rows per block

// ---------------- Phase A: per-split partial attention ----------------
__global__ __launch_bounds__(256) void attn_partial(
    const float* __restrict__ q,
    const float* __restrict__ k,
    const float* __restrict__ v,
    float* __restrict__ outp,   // [B][SPLIT][Mh][H]
    float* __restrict__ mxw,    // [B][SPLIT][Mh]
    float* __restrict__ smw)    // [B][SPLIT][Mh]
{
    __shared__ float4 q4s[MH4];       // 16 KB: q[b,:] (all heads)
    __shared__ float  sc[Mh][TBLK];   // 2 KB: scores -> probs

    const int bid = blockIdx.x;
    const int b   = bid / SPLIT;
    const int sp  = bid % SPLIT;
    const int t0  = sp * TBLK;
    const int tid = threadIdx.x;
    const int w    = tid >> 6;
    const int lane = tid & 63;

    // stage q[b,:,:] (16 KB), coalesced
    const float4* q4 = (const float4*)q + (size_t)b * MH4;
#pragma unroll
    for (int j = 0; j < 4; ++j) q4s[tid + j * 256] = q4[tid + j * 256];
    __syncthreads();

    // ---- scores: s[m][t] = q[m]·k[t,m] ----
    const float4* k4 = (const float4*)k + (size_t)(b * KVT + t0) * MH4;
#pragma unroll 4
    for (int t = 0; t < TBLK; ++t) {
        const float4* kr = k4 + (size_t)t * MH4;
#pragma unroll
        for (int i = 0; i < 4; ++i) {
            const int f = w * 256 + i * 64 + lane;   // contiguous 1KB per instr
            float4 kk = kr[f];
            float4 qq = q4s[f];
            float d = kk.x * qq.x + kk.y * qq.y + kk.z * qq.z + kk.w * qq.w;
            // sum over the 32 lanes sharing one head (half-wave butterfly)
#pragma unroll
            for (int off = 16; off; off >>= 1) d += __shfl_xor(d, off);
            if ((lane & 31) == 0)
                sc[w * 8 + 2 * i + (lane >> 5)][t] = d;
        }
    }
    __syncthreads();

    // ---- per-head partial softmax over this block's TBLK scores ----
    {
        const int g = tid & 7;        // 8 lanes per head
        const int m = tid >> 3;       // 0..31
        float s0 = sc[m][g], s1 = sc[m][g + 8];
        float mx = fmaxf(s0, s1);
#pragma unroll
        for (int off = 1; off < 8; off <<= 1) mx = fmaxf(mx, __shfl_xor(mx, off));
        float p0 = __expf(s0 - mx), p1 = __expf(s1 - mx);
        float ss = p0 + p1;
#pragma unroll
        for (int off = 1; off < 8; off <<= 1) ss += __shfl_xor(ss, off);
        sc[m][g] = p0; sc[m][g + 8] = p1;
        if (g == 0) {
            mxw[(size_t)bid * Mh + m] = mx;
            smw[(size_t)bid * Mh + m] = ss;
        }
    }
    __syncthreads();

    // ---- PV: outp[m][h] = sum_t p[m][t] * v[t,m,h] ----
    float4 acc[4];
#pragma unroll
    for (int i = 0; i < 4; ++i) acc[i] = make_float4(0.f, 0.f, 0.f, 0.f);
    int mi[4];
#pragma unroll
    for (int i = 0; i < 4; ++i) mi[i] = w * 8 + 2 * i + (lane >> 5);

    const float4* v4 = (const float4*)v + (size_t)(b * KVT + t0) * MH4;
#pragma unroll 4
    for (int t = 0; t < TBLK; ++t) {
        const float4* vr = v4 + (size_t)t * MH4;
#pragma unroll
        for (int i = 0; i < 4; ++i) {
            float  p  = sc[mi[i]][t];                // 2-addr LDS broadcast
            float4 vv = vr[w * 256 + i * 64 + lane]; // contiguous 1KB per instr
            acc[i].x += p * vv.x; acc[i].y += p * vv.y;
            acc[i].z += p * vv.z; acc[i].w += p * vv.w;
        }
    }
    float4* op4 = (float4*)outp + (size_t)bid * MH4;
#pragma unroll
    for (int i = 0; i < 4; ++i) op4[w * 256 + i * 64 + lane] = acc[i];
}

// ---------------- Phase B: combine splits ----------------
__global__ __launch_bounds__(64) void attn_combine(
    const float* __restrict__ outp,
    const float* __restrict__ mxw,
    const float* __restrict__ smw,
    float* __restrict__ out)
{
    const int bm  = blockIdx.x;          // b*32 + m
    const int b   = bm >> 5;
    const int m   = bm & 31;
    const int tid = threadIdx.x;

    float mxs[SPLIT];
    float mg = -3.0e38f;
#pragma unroll
    for (int s = 0; s < SPLIT; ++s) {
        mxs[s] = mxw[(size_t)(b * SPLIT + s) * Mh + m];
        mg = fmaxf(mg, mxs[s]);
    }
    float wsc[SPLIT];
    float sg = 0.f;
#pragma unroll
    for (int s = 0; s < SPLIT; ++s) {
        wsc[s] = __expf(mxs[s] - mg);
        sg += wsc[s] * smw[(size_t)(b * SPLIT + s) * Mh + m];
    }
    const float inv = 1.f / sg;

    if (tid < 32) {
        float4 o = make_float4(0.f, 0.f, 0.f, 0.f);
#pragma unroll
        for (int s = 0; s < SPLIT; ++s) {
            float4 t4 = ((const float4*)outp)[(size_t)(b * SPLIT + s) * MH4 + m * 32 + tid];
            o.x += wsc[s] * t4.x; o.y += wsc[s] * t4.y;
            o.z += wsc[s] * t4.z; o.w += wsc[s] * t4.w;
        }
        o.x *= inv; o.y *= inv; o.z *= inv; o.w *= inv;
        ((float4*)out)[(size_t)bm * 32 + tid] = o;
    }
}

// ---------------- Fallback (R1 kernel) if ws is too small ----------------
__global__ __launch_bounds__(256) void mme_attn_fallback(
    const float* __restrict__ q, const float* __restrict__ k,
    const float* __restrict__ v, float* __restrict__ out)
{
    __shared__ float  q_s[H];
    __shared__ float  sc[KVT];
    __shared__ float  red[8];
    __shared__ float4 o4[256];

    const int bm = blockIdx.x, b = bm >> 5, m = bm & 31, tid = threadIdx.x;
    const size_t kbase = (size_t)b * KVT * MH + (size_t)m * H;
    if (tid < H) q_s[tid] = q[(size_t)b * MH + (size_t)m * H + tid];
    __syncthreads();
    float s;
    {
        const float4* kp = (const float4*)(k + kbase + (size_t)tid * MH);
        const float4* qp = (const float4*)q_s;
        float acc = 0.f;
#pragma unroll
        for (int i = 0; i < H / 4; ++i) {
            float4 kk = kp[i]; float4 qq = qp[i];
            acc += kk.x * qq.x + kk.y * qq.y + kk.z * qq.z + kk.w * qq.w;
        }
        s = acc;
    }
    const int lane = tid & 63, wv = tid >> 6;
    float mx = s;
#pragma unroll
    for (int off = 32; off > 0; off >>= 1) mx = fmaxf(mx, __shfl_xor(mx, off));
    if (lane == 0) red[wv] = mx;
    __syncthreads();
    mx = fmaxf(fmaxf(red[0], red[1]), fmaxf(red[2], red[3]));
    float p = __expf(s - mx), sm = p;
#pragma unroll
    for (int off = 32; off > 0; off >>= 1) sm += __shfl_xor(sm, off);
    if (lane == 0) red[4 + wv] = sm;
    __syncthreads();
    sm = (red[4] + red[5]) + (red[6] + red[7]);
    sc[tid] = p * __frcp_rn(sm);
    __syncthreads();
    const int c4 = tid & 31, seg = tid >> 5;
    float4 acc4 = {0.f, 0.f, 0.f, 0.f};
    const float* vb = v + kbase + (size_t)c4 * 4;
#pragma unroll 4
    for (int t = seg * 32; t < seg * 32 + 32; ++t) {
        float pt = sc[t];
        float4 vv = *(const float4*)(vb + (size_t)t * MH);
        acc4.x += pt * vv.x; acc4.y += pt * vv.y;
        acc4.z += pt * vv.z; acc4.w += pt * vv.w;
    }
    o4[tid] = acc4;
    __syncthreads();
    if (tid < 32) {
        float4 r = o4[tid];
#pragma unroll
        for (int sgi = 1; sgi < 8; ++sgi) {
            float4 t4 = o4[sgi * 32 + tid];
            r.x += t4.x; r.y += t4.y; r.z += t4.z; r.w += t4.w;
        }
        ((float4*)(out + (size_t)bm * H))[tid] = r;
    }
}

extern "C" void kernel_launch(void* const* d_in, const int* in_sizes, int n_in,
                              void* d_out, int out_size, void* d_ws, size_t ws_size,
                              hipStream_t stream) {
    const float* q = (const float*)d_in[0];
    const float* k = (const float*)d_in[1];
    const float* v = (const float*)d_in[2];
    float* out = (float*)d_out;

    const size_t n_outp = (size_t)B * SPLIT * MH;        // 4 Mi floats
    const size_t n_stat = (size_t)B * SPLIT * Mh;        // 32 Ki floats
    const size_t need   = (n_outp + 2 * n_stat) * sizeof(float);

    if (ws_size >= need) {
        float* outp = (float*)d_ws;
        float* mxw  = outp + n_outp;
        float* smw  = mxw + n_stat;
        attn_partial<<<B * SPLIT, 256, 0, stream>>>(q, k, v, outp, mxw, smw);
        attn_combine<<<B * Mh, 64, 0, stream>>>(outp, mxw, smw, out);
    } else {
        mme_attn_fallback<<<B * Mh, 256, 0, stream>>>(q, k, v, out);
    }
}